// Round 1
// baseline (2553.933 us; speedup 1.0000x reference)
//
#include <hip/hip_runtime.h>

// Problem constants (reference: N=2048, A=100)
#define NN 2048
#define AA 100
#define NT 32   // 64-wide tiles per side (2048/64)

// ---------------------------------------------------------------------------
// Kernel 1: build w[i][j] = min(f(mg[i][j]*nw[i]), f(mg[j][i]*nw[j])), f(x)=x>0?x:inf,
// diag=0. Transpose element fetched via LDS tile to keep both reads coalesced.
// ---------------------------------------------------------------------------
__global__ __launch_bounds__(256) void build_w_kernel(
    const float* __restrict__ mg, const float* __restrict__ nw,
    float* __restrict__ w) {
  __shared__ float Tt[64][65];
  int bi = blockIdx.y, bj = blockIdx.x;
  int t = threadIdx.x;
#pragma unroll
  for (int l = 0; l < 16; ++l) {
    int idx = l * 256 + t;
    int r = idx >> 6, c = idx & 63;
    // Tt[x][y] = mg[(bj*64+y)][bi*64+x]
    Tt[c][r] = mg[(bj * 64 + r) * NN + bi * 64 + c];
  }
  __syncthreads();
#pragma unroll
  for (int l = 0; l < 16; ++l) {
    int idx = l * 256 + t;
    int r = idx >> 6, c = idx & 63;
    int i = bi * 64 + r, j = bj * 64 + c;
    float a = mg[i * NN + j] * nw[i];
    float b = Tt[r][c] * nw[j];   // = mg[j][i] * nw[j]
    float wa = a > 0.0f ? a : __builtin_huge_valf();
    float wb = b > 0.0f ? b : __builtin_huge_valf();
    float v = fminf(wa, wb);
    if (i == j) v = 0.0f;
    w[i * NN + j] = v;            // scalar store: dist may be only 4B-aligned
  }
}

// ---------------------------------------------------------------------------
// Blocked Floyd–Warshall, tile = 64x64, 256 threads, 4x4 register micro-tile.
// ---------------------------------------------------------------------------

// select helper (avoids dynamic register-array indexing -> scratch spill)
__device__ __forceinline__ float sel4(float x0, float x1, float x2, float x3, int j) {
  return j == 0 ? x0 : (j == 1 ? x1 : (j == 2 ? x2 : x3));
}

// Phase 1: in-tile FW closure of diagonal tile (r,r). Registers hold each
// thread's 4x4 cells; only column/row k+1 is published to LDS per step, so
// iteration k's reads (col/row k) never race with writes (col/row k+1) except
// cells (k,k+1)/(k+1,k) whose rewritten value is bitwise identical (d[k][k]=0).
__global__ __launch_bounds__(256) void fw_phase1(float* __restrict__ d, int r) {
  __shared__ __align__(16) float Ts[64][68];
  int t = threadIdx.x;
  int tx = t & 15, ty = t >> 4;
  int i0 = ty * 4, j0 = tx * 4;
  int base = (r * 64) * NN + r * 64;
#pragma unroll
  for (int l = 0; l < 16; ++l) {
    int idx = l * 256 + t;
    int row = idx >> 6, col = idx & 63;
    Ts[row][col] = d[base + row * NN + col];
  }
  __syncthreads();
  float c[4][4];
#pragma unroll
  for (int ii = 0; ii < 4; ++ii)
#pragma unroll
    for (int jj = 0; jj < 4; ++jj) c[ii][jj] = Ts[i0 + ii][j0 + jj];

  for (int k = 0; k < 64; ++k) {
    float a0 = Ts[i0 + 0][k], a1 = Ts[i0 + 1][k], a2 = Ts[i0 + 2][k], a3 = Ts[i0 + 3][k];
    float4 b = *(const float4*)&Ts[k][j0];
    c[0][0] = fminf(c[0][0], a0 + b.x); c[0][1] = fminf(c[0][1], a0 + b.y);
    c[0][2] = fminf(c[0][2], a0 + b.z); c[0][3] = fminf(c[0][3], a0 + b.w);
    c[1][0] = fminf(c[1][0], a1 + b.x); c[1][1] = fminf(c[1][1], a1 + b.y);
    c[1][2] = fminf(c[1][2], a1 + b.z); c[1][3] = fminf(c[1][3], a1 + b.w);
    c[2][0] = fminf(c[2][0], a2 + b.x); c[2][1] = fminf(c[2][1], a2 + b.y);
    c[2][2] = fminf(c[2][2], a2 + b.z); c[2][3] = fminf(c[2][3], a2 + b.w);
    c[3][0] = fminf(c[3][0], a3 + b.x); c[3][1] = fminf(c[3][1], a3 + b.y);
    c[3][2] = fminf(c[3][2], a3 + b.z); c[3][3] = fminf(c[3][3], a3 + b.w);
    int kn = k + 1;
    if (kn < 64) {
      if (kn >= j0 && kn < j0 + 4) {   // publish my piece of column k+1
        int jj = kn - j0;
        Ts[i0 + 0][kn] = sel4(c[0][0], c[0][1], c[0][2], c[0][3], jj);
        Ts[i0 + 1][kn] = sel4(c[1][0], c[1][1], c[1][2], c[1][3], jj);
        Ts[i0 + 2][kn] = sel4(c[2][0], c[2][1], c[2][2], c[2][3], jj);
        Ts[i0 + 3][kn] = sel4(c[3][0], c[3][1], c[3][2], c[3][3], jj);
      }
      if (kn >= i0 && kn < i0 + 4) {   // publish my piece of row k+1
        int ii = kn - i0;
        Ts[kn][j0 + 0] = sel4(c[0][0], c[1][0], c[2][0], c[3][0], ii);
        Ts[kn][j0 + 1] = sel4(c[0][1], c[1][1], c[2][1], c[3][1], ii);
        Ts[kn][j0 + 2] = sel4(c[0][2], c[1][2], c[2][2], c[3][2], ii);
        Ts[kn][j0 + 3] = sel4(c[0][3], c[1][3], c[2][3], c[3][3], ii);
      }
    }
    __syncthreads();
  }
#pragma unroll
  for (int ii = 0; ii < 4; ++ii)
#pragma unroll
    for (int jj = 0; jj < 4; ++jj)
      d[base + (i0 + ii) * NN + (j0 + jj)] = c[ii][jj];
}

// One-pass min-plus tile update: out = min(out_old, A (minplus) B).
__device__ __forceinline__ void minplus_body(
    float* __restrict__ d, float (*As)[68], float (*Bs)[68],
    int aR, int aC, int bR, int bC, int oR, int oC) {
  int t = threadIdx.x;
#pragma unroll
  for (int l = 0; l < 16; ++l) {
    int idx = l * 256 + t;
    int row = idx >> 6, col = idx & 63;
    As[row][col] = d[(aR * 64 + row) * NN + aC * 64 + col];
    Bs[row][col] = d[(bR * 64 + row) * NN + bC * 64 + col];
  }
  int tx = t & 15, ty = t >> 4;
  int i0 = ty * 4, j0 = tx * 4;
  float c[4][4];
#pragma unroll
  for (int ii = 0; ii < 4; ++ii)
#pragma unroll
    for (int jj = 0; jj < 4; ++jj)
      c[ii][jj] = d[(oR * 64 + i0 + ii) * NN + oC * 64 + j0 + jj];
  __syncthreads();
#pragma unroll 4
  for (int k = 0; k < 64; ++k) {
    float a0 = As[i0 + 0][k], a1 = As[i0 + 1][k], a2 = As[i0 + 2][k], a3 = As[i0 + 3][k];
    float4 b = *(const float4*)&Bs[k][j0];
    c[0][0] = fminf(c[0][0], a0 + b.x); c[0][1] = fminf(c[0][1], a0 + b.y);
    c[0][2] = fminf(c[0][2], a0 + b.z); c[0][3] = fminf(c[0][3], a0 + b.w);
    c[1][0] = fminf(c[1][0], a1 + b.x); c[1][1] = fminf(c[1][1], a1 + b.y);
    c[1][2] = fminf(c[1][2], a1 + b.z); c[1][3] = fminf(c[1][3], a1 + b.w);
    c[2][0] = fminf(c[2][0], a2 + b.x); c[2][1] = fminf(c[2][1], a2 + b.y);
    c[2][2] = fminf(c[2][2], a2 + b.z); c[2][3] = fminf(c[2][3], a2 + b.w);
    c[3][0] = fminf(c[3][0], a3 + b.x); c[3][1] = fminf(c[3][1], a3 + b.y);
    c[3][2] = fminf(c[3][2], a3 + b.z); c[3][3] = fminf(c[3][3], a3 + b.w);
  }
#pragma unroll
  for (int ii = 0; ii < 4; ++ii)
#pragma unroll
    for (int jj = 0; jj < 4; ++jj)
      d[(oR * 64 + i0 + ii) * NN + oC * 64 + j0 + jj] = c[ii][jj];
}

// Phase 2: row tiles (r,t): C = diag (x) C ; col tiles (t,r): C = C (x) diag.
__global__ __launch_bounds__(256) void fw_phase2(float* __restrict__ d, int r) {
  __shared__ __align__(16) float As[64][68];
  __shared__ __align__(16) float Bs[64][68];
  int t = blockIdx.x;
  if (t == r) return;
  if (blockIdx.y == 0) minplus_body(d, As, Bs, r, r, r, t, r, t);
  else                 minplus_body(d, As, Bs, t, r, r, r, t, r);
}

// Phase 3: all remaining tiles (by,bx): C = min(C, (by,r) (x) (r,bx)).
// Skip row/col r (removes read-write overlap with no extra launches).
__global__ __launch_bounds__(256) void fw_phase3(float* __restrict__ d, int r) {
  __shared__ __align__(16) float As[64][68];
  __shared__ __align__(16) float Bs[64][68];
  int bx = blockIdx.x, by = blockIdx.y;
  if (bx == r || by == r) return;
  minplus_body(d, As, Bs, by, r, r, bx, by, bx);
}

// ---------------------------------------------------------------------------
// anchors[rank] = i for rank < A, rank = #{j: nw[j]>nw[i]} + #{j<i: nw[j]==nw[i]}
// == stable argsort(-nw) positions.
// ---------------------------------------------------------------------------
__global__ __launch_bounds__(256) void anchors_kernel(
    const float* __restrict__ nw, int* __restrict__ anchors) {
  int i = blockIdx.x * 256 + threadIdx.x;
  float wi = nw[i];
  int rank = 0;
  for (int j = 0; j < NN; ++j) {
    float wj = nw[j];
    rank += (wj > wi) || (wj == wi && j < i);
  }
  if (rank < AA) anchors[rank] = i;
}

// ---------------------------------------------------------------------------
// Gather consensus_vectors (inf -> 100), accumulate global sum for the scalar.
// ---------------------------------------------------------------------------
__global__ __launch_bounds__(256) void cv_kernel(
    const float* __restrict__ dist, const int* __restrict__ anchors,
    float* __restrict__ cv_out, float* __restrict__ sum_acc) {
  int idx = blockIdx.x * 256 + threadIdx.x;   // 800*256 == 204800 exactly
  int i = idx / 100, a = idx - i * 100;
  float dv = dist[i * NN + anchors[a]];
  if (isinf(dv)) dv = 100.0f;
  cv_out[idx] = dv;
  float v = dv;
#pragma unroll
  for (int off = 32; off > 0; off >>= 1) v += __shfl_down(v, off);
  __shared__ float sv[4];
  int lane = threadIdx.x & 63, w = threadIdx.x >> 6;
  if (lane == 0) sv[w] = v;
  __syncthreads();
  if (threadIdx.x == 0) atomicAdd(sum_acc, sv[0] + sv[1] + sv[2] + sv[3]);
}

// ---------------------------------------------------------------------------
// consensus_graph: weighted = wm*cv computed on the fly; per-row xx computed
// in-block (identical arithmetic for i- and j-tiles); K=100 f32 dot + epilogue.
// ---------------------------------------------------------------------------
__global__ __launch_bounds__(256) void graph_kernel(
    const float* __restrict__ wm, const float* __restrict__ cv,
    const float* __restrict__ sigma, float* __restrict__ graph) {
  __shared__ __align__(16) float As[64][108];
  __shared__ __align__(16) float Bs[64][108];
  __shared__ float xs[64], ys[64];
  int bx = blockIdx.x, by = blockIdx.y;
  int t = threadIdx.x;
#pragma unroll
  for (int l = 0; l < 7; ++l) {
    int idx = l * 256 + t;
    if (idx < 1600) {                 // 64 rows * 25 float4
      int row = idx / 25, c4 = (idx - row * 25) * 4;
      float4 wa = *(const float4*)&wm[(by * 64 + row) * AA + c4];
      float4 ca = *(const float4*)&cv[(by * 64 + row) * AA + c4];
      *(float4*)&As[row][c4] =
          make_float4(wa.x * ca.x, wa.y * ca.y, wa.z * ca.z, wa.w * ca.w);
      float4 wb = *(const float4*)&wm[(bx * 64 + row) * AA + c4];
      float4 cb = *(const float4*)&cv[(bx * 64 + row) * AA + c4];
      *(float4*)&Bs[row][c4] =
          make_float4(wb.x * cb.x, wb.y * cb.y, wb.z * cb.z, wb.w * cb.w);
    }
  }
  __syncthreads();
  if (t < 64) {
    float s = 0.0f;
    for (int k4 = 0; k4 < 25; ++k4) {
      float4 q = *(const float4*)&As[t][k4 * 4];
      s += q.x * q.x + q.y * q.y + q.z * q.z + q.w * q.w;
    }
    xs[t] = s;
  } else if (t < 128) {
    int r = t - 64;
    float s = 0.0f;
    for (int k4 = 0; k4 < 25; ++k4) {
      float4 q = *(const float4*)&Bs[r][k4 * 4];
      s += q.x * q.x + q.y * q.y + q.z * q.z + q.w * q.w;
    }
    ys[r] = s;
  }
  __syncthreads();
  int tx = t & 15, ty = t >> 4;
  float acc[4][4] = {{0.0f}};
#pragma unroll 5
  for (int k4 = 0; k4 < 25; ++k4) {
    int k = k4 * 4;
    float4 a_[4], b_[4];
#pragma unroll
    for (int ii = 0; ii < 4; ++ii) a_[ii] = *(const float4*)&As[ty + 16 * ii][k];
#pragma unroll
    for (int jj = 0; jj < 4; ++jj) b_[jj] = *(const float4*)&Bs[tx + 16 * jj][k];
#pragma unroll
    for (int ii = 0; ii < 4; ++ii)
#pragma unroll
      for (int jj = 0; jj < 4; ++jj)
        acc[ii][jj] += a_[ii].x * b_[jj].x + a_[ii].y * b_[jj].y +
                       a_[ii].z * b_[jj].z + a_[ii].w * b_[jj].w;
  }
  float s = *sigma;
  float inv2s2 = 0.5f / (s * s);
#pragma unroll
  for (int ii = 0; ii < 4; ++ii) {
    int gi = by * 64 + ty + 16 * ii;
    float xi = xs[ty + 16 * ii];
#pragma unroll
    for (int jj = 0; jj < 4; ++jj) {
      int gj = bx * 64 + tx + 16 * jj;
      float sq = fmaxf(xi + ys[tx + 16 * jj] - 2.0f * acc[ii][jj], 0.0f);
      graph[gi * NN + gj] = __expf(-(sq * sq) * inv2s2);  // scalar store: base may be 4B-aligned
    }
  }
}

__global__ void finalize_kernel(const float* __restrict__ sum_acc,
                                float* __restrict__ out) {
  if (threadIdx.x == 0)
    *out = (*sum_acc - 204800.0f) / 204800.0f;  // (sum - N*100) / (N*A)
}

// ---------------------------------------------------------------------------
extern "C" void kernel_launch(void* const* d_in, const int* in_sizes, int n_in,
                              void* d_out, int out_size, void* d_ws, size_t ws_size,
                              hipStream_t stream) {
  (void)in_sizes; (void)n_in; (void)out_size;
  const float* mg    = (const float*)d_in[0];
  const float* nw    = (const float*)d_in[1];
  const float* wm    = (const float*)d_in[2];
  const float* sigma = (const float*)d_in[3];
  float* out        = (float*)d_out;
  float* cv_out     = out;            // 2048*100
  float* scalar_out = out + 204800;   // 1
  float* graph_out  = out + 204801;   // 2048*2048

  float* W = (float*)d_ws;
  float* sum_acc = W;                 // 1 float
  int* anchors   = (int*)(W + 4);     // 100 ints
  float* dist;
  if (ws_size >= (size_t)(256 + (size_t)NN * NN) * sizeof(float)) {
    dist = W + 256;                   // 16 MB scratch, 16B-aligned (unused here: all dist I/O is b32)
  } else {
    // Fallback: alias dist onto the consensus_graph output region (4B-aligned —
    // every global access to dist is scalar b32). graph_kernel fully overwrites
    // it AFTER cv_kernel has extracted the anchor columns.
    dist = graph_out;
  }

  hipMemsetAsync(sum_acc, 0, sizeof(float), stream);
  build_w_kernel<<<dim3(NT, NT), 256, 0, stream>>>(mg, nw, dist);
  for (int r = 0; r < NT; ++r) {
    fw_phase1<<<1, 256, 0, stream>>>(dist, r);
    fw_phase2<<<dim3(NT, 2), 256, 0, stream>>>(dist, r);
    fw_phase3<<<dim3(NT, NT), 256, 0, stream>>>(dist, r);
  }
  anchors_kernel<<<NN / 256, 256, 0, stream>>>(nw, anchors);
  cv_kernel<<<800, 256, 0, stream>>>(dist, anchors, cv_out, sum_acc);
  graph_kernel<<<dim3(NT, NT), 256, 0, stream>>>(wm, cv_out, sigma, graph_out);
  finalize_kernel<<<1, 64, 0, stream>>>(sum_acc, scalar_out);
}

// Round 2
// 2494.704 us; speedup vs baseline: 1.0237x; 1.0237x over previous
//
#include <hip/hip_runtime.h>

// Problem constants (reference: N=2048, A=100)
#define NN 2048
#define AA 100
#define NT 32   // 64-wide tiles per side (2048/64)

// ---------------------------------------------------------------------------
// Kernel 1: build w[i][j] = min(f(mg[i][j]*nw[i]), f(mg[j][i]*nw[j])), f(x)=x>0?x:inf,
// diag=0. Transpose element fetched via LDS tile to keep both reads coalesced.
// ---------------------------------------------------------------------------
__global__ __launch_bounds__(256) void build_w_kernel(
    const float* __restrict__ mg, const float* __restrict__ nw,
    float* __restrict__ w) {
  __shared__ float Tt[64][65];
  int bi = blockIdx.y, bj = blockIdx.x;
  int t = threadIdx.x;
#pragma unroll
  for (int l = 0; l < 16; ++l) {
    int idx = l * 256 + t;
    int r = idx >> 6, c = idx & 63;
    // Tt[x][y] = mg[(bj*64+y)][bi*64+x]
    Tt[c][r] = mg[(bj * 64 + r) * NN + bi * 64 + c];
  }
  __syncthreads();
#pragma unroll
  for (int l = 0; l < 16; ++l) {
    int idx = l * 256 + t;
    int r = idx >> 6, c = idx & 63;
    int i = bi * 64 + r, j = bj * 64 + c;
    float a = mg[i * NN + j] * nw[i];
    float b = Tt[r][c] * nw[j];   // = mg[j][i] * nw[j]
    float wa = a > 0.0f ? a : __builtin_huge_valf();
    float wb = b > 0.0f ? b : __builtin_huge_valf();
    float v = fminf(wa, wb);
    if (i == j) v = 0.0f;
    w[i * NN + j] = v;            // scalar store: dist may be only 4B-aligned
  }
}

// ---------------------------------------------------------------------------
// Blocked Floyd–Warshall, tile = 64x64, 256 threads, 4x4 register micro-tile.
// ---------------------------------------------------------------------------

// select helper (avoids dynamic register-array indexing -> scratch spill)
__device__ __forceinline__ float sel4(float x0, float x1, float x2, float x3, int j) {
  return j == 0 ? x0 : (j == 1 ? x1 : (j == 2 ? x2 : x3));
}

// In-LDS FW closure of the diagonal tile held in Ts. 256 threads, 4x4 regs.
// Only column/row k+1 is published per step, so iteration k's reads (col/row k)
// never race with writes (col/row k+1); cells (k,k+1)/(k+1,k) rewrite bitwise-
// identical values (d[k][k]=0). On exit Ts holds the closed tile.
__device__ __forceinline__ void close_diag_in_lds(float (*Ts)[68]) {
  int t = threadIdx.x;
  int tx = t & 15, ty = t >> 4;
  int i0 = ty * 4, j0 = tx * 4;
  float c[4][4];
#pragma unroll
  for (int ii = 0; ii < 4; ++ii)
#pragma unroll
    for (int jj = 0; jj < 4; ++jj) c[ii][jj] = Ts[i0 + ii][j0 + jj];

  for (int k = 0; k < 64; ++k) {
    float a0 = Ts[i0 + 0][k], a1 = Ts[i0 + 1][k], a2 = Ts[i0 + 2][k], a3 = Ts[i0 + 3][k];
    float4 b = *(const float4*)&Ts[k][j0];
    c[0][0] = fminf(c[0][0], a0 + b.x); c[0][1] = fminf(c[0][1], a0 + b.y);
    c[0][2] = fminf(c[0][2], a0 + b.z); c[0][3] = fminf(c[0][3], a0 + b.w);
    c[1][0] = fminf(c[1][0], a1 + b.x); c[1][1] = fminf(c[1][1], a1 + b.y);
    c[1][2] = fminf(c[1][2], a1 + b.z); c[1][3] = fminf(c[1][3], a1 + b.w);
    c[2][0] = fminf(c[2][0], a2 + b.x); c[2][1] = fminf(c[2][1], a2 + b.y);
    c[2][2] = fminf(c[2][2], a2 + b.z); c[2][3] = fminf(c[2][3], a2 + b.w);
    c[3][0] = fminf(c[3][0], a3 + b.x); c[3][1] = fminf(c[3][1], a3 + b.y);
    c[3][2] = fminf(c[3][2], a3 + b.z); c[3][3] = fminf(c[3][3], a3 + b.w);
    int kn = k + 1;
    if (kn < 64) {
      if (kn >= j0 && kn < j0 + 4) {   // publish my piece of column k+1
        int jj = kn - j0;
        Ts[i0 + 0][kn] = sel4(c[0][0], c[0][1], c[0][2], c[0][3], jj);
        Ts[i0 + 1][kn] = sel4(c[1][0], c[1][1], c[1][2], c[1][3], jj);
        Ts[i0 + 2][kn] = sel4(c[2][0], c[2][1], c[2][2], c[2][3], jj);
        Ts[i0 + 3][kn] = sel4(c[3][0], c[3][1], c[3][2], c[3][3], jj);
      }
      if (kn >= i0 && kn < i0 + 4) {   // publish my piece of row k+1
        int ii = kn - i0;
        Ts[kn][j0 + 0] = sel4(c[0][0], c[1][0], c[2][0], c[3][0], ii);
        Ts[kn][j0 + 1] = sel4(c[0][1], c[1][1], c[2][1], c[3][1], ii);
        Ts[kn][j0 + 2] = sel4(c[0][2], c[1][2], c[2][2], c[3][2], ii);
        Ts[kn][j0 + 3] = sel4(c[0][3], c[1][3], c[2][3], c[3][3], ii);
      }
    }
    __syncthreads();
  }
  // publish the fully-closed tile back into Ts
#pragma unroll
  for (int ii = 0; ii < 4; ++ii)
#pragma unroll
    for (int jj = 0; jj < 4; ++jj) Ts[i0 + ii][j0 + jj] = c[ii][jj];
  __syncthreads();
}

// Fused phase1+phase2: every block redundantly closes the diagonal tile (r,r)
// in LDS (reads the PRE-closure global values, so all blocks see identical
// input), then:
//   block (r, 0)  : stores the closed diag back to global
//   block (t, 0)  : row tile   C(r,t) = min(C, diag (x) C)    [A = closed diag]
//   block (t, 1)  : col tile   C(t,r) = min(C, C (x) diag)    [B = closed diag]
// One-pass in-place update is valid because diag is transitively closed.
__global__ __launch_bounds__(256) void fw_p12(float* __restrict__ d, int r) {
  __shared__ __align__(16) float Ts[64][68];   // closed diagonal tile
  __shared__ __align__(16) float Us[64][68];   // this block's own tile (old values)
  int tile = blockIdx.x, side = blockIdx.y;
  if (tile == r && side == 1) return;
  int t = threadIdx.x;
  int dbase = (r * 64) * NN + r * 64;
#pragma unroll
  for (int l = 0; l < 16; ++l) {
    int idx = l * 256 + t;
    int row = idx >> 6, col = idx & 63;
    Ts[row][col] = d[dbase + row * NN + col];
  }
  __syncthreads();
  close_diag_in_lds(Ts);

  if (tile == r) {  // side==0: write closed diag, done
#pragma unroll
    for (int l = 0; l < 16; ++l) {
      int idx = l * 256 + t;
      int row = idx >> 6, col = idx & 63;
      d[dbase + row * NN + col] = Ts[row][col];
    }
    return;
  }

  int obase = (side == 0) ? (r * 64) * NN + tile * 64
                          : (tile * 64) * NN + r * 64;
#pragma unroll
  for (int l = 0; l < 16; ++l) {
    int idx = l * 256 + t;
    int row = idx >> 6, col = idx & 63;
    Us[row][col] = d[obase + row * NN + col];
  }
  __syncthreads();

  int tx = t & 15, ty = t >> 4;
  int i0 = ty * 4, j0 = tx * 4;
  float c[4][4];
#pragma unroll
  for (int ii = 0; ii < 4; ++ii)
#pragma unroll
    for (int jj = 0; jj < 4; ++jj) c[ii][jj] = Us[i0 + ii][j0 + jj];

  float (*Ap)[68] = (side == 0) ? Ts : Us;  // A operand
  float (*Bp)[68] = (side == 0) ? Us : Ts;  // B operand
#pragma unroll 4
  for (int k = 0; k < 64; ++k) {
    float a0 = Ap[i0 + 0][k], a1 = Ap[i0 + 1][k], a2 = Ap[i0 + 2][k], a3 = Ap[i0 + 3][k];
    float4 b = *(const float4*)&Bp[k][j0];
    c[0][0] = fminf(c[0][0], a0 + b.x); c[0][1] = fminf(c[0][1], a0 + b.y);
    c[0][2] = fminf(c[0][2], a0 + b.z); c[0][3] = fminf(c[0][3], a0 + b.w);
    c[1][0] = fminf(c[1][0], a1 + b.x); c[1][1] = fminf(c[1][1], a1 + b.y);
    c[1][2] = fminf(c[1][2], a1 + b.z); c[1][3] = fminf(c[1][3], a1 + b.w);
    c[2][0] = fminf(c[2][0], a2 + b.x); c[2][1] = fminf(c[2][1], a2 + b.y);
    c[2][2] = fminf(c[2][2], a2 + b.z); c[2][3] = fminf(c[2][3], a2 + b.w);
    c[3][0] = fminf(c[3][0], a3 + b.x); c[3][1] = fminf(c[3][1], a3 + b.y);
    c[3][2] = fminf(c[3][2], a3 + b.z); c[3][3] = fminf(c[3][3], a3 + b.w);
  }
#pragma unroll
  for (int ii = 0; ii < 4; ++ii)
#pragma unroll
    for (int jj = 0; jj < 4; ++jj)
      d[obase + (i0 + ii) * NN + (j0 + jj)] = c[ii][jj];
}

// Phase 3: all remaining tiles (by,bx): C = min(C, (by,r) (x) (r,bx)).
__global__ __launch_bounds__(256) void fw_phase3(float* __restrict__ d, int r) {
  __shared__ __align__(16) float As[64][68];
  __shared__ __align__(16) float Bs[64][68];
  int bx = blockIdx.x, by = blockIdx.y;
  if (bx == r || by == r) return;
  int t = threadIdx.x;
#pragma unroll
  for (int l = 0; l < 16; ++l) {
    int idx = l * 256 + t;
    int row = idx >> 6, col = idx & 63;
    As[row][col] = d[(by * 64 + row) * NN + r * 64 + col];
    Bs[row][col] = d[(r * 64 + row) * NN + bx * 64 + col];
  }
  int tx = t & 15, ty = t >> 4;
  int i0 = ty * 4, j0 = tx * 4;
  float c[4][4];
#pragma unroll
  for (int ii = 0; ii < 4; ++ii)
#pragma unroll
    for (int jj = 0; jj < 4; ++jj)
      c[ii][jj] = d[(by * 64 + i0 + ii) * NN + bx * 64 + j0 + jj];
  __syncthreads();
#pragma unroll 4
  for (int k = 0; k < 64; ++k) {
    float a0 = As[i0 + 0][k], a1 = As[i0 + 1][k], a2 = As[i0 + 2][k], a3 = As[i0 + 3][k];
    float4 b = *(const float4*)&Bs[k][j0];
    c[0][0] = fminf(c[0][0], a0 + b.x); c[0][1] = fminf(c[0][1], a0 + b.y);
    c[0][2] = fminf(c[0][2], a0 + b.z); c[0][3] = fminf(c[0][3], a0 + b.w);
    c[1][0] = fminf(c[1][0], a1 + b.x); c[1][1] = fminf(c[1][1], a1 + b.y);
    c[1][2] = fminf(c[1][2], a1 + b.z); c[1][3] = fminf(c[1][3], a1 + b.w);
    c[2][0] = fminf(c[2][0], a2 + b.x); c[2][1] = fminf(c[2][1], a2 + b.y);
    c[2][2] = fminf(c[2][2], a2 + b.z); c[2][3] = fminf(c[2][3], a2 + b.w);
    c[3][0] = fminf(c[3][0], a3 + b.x); c[3][1] = fminf(c[3][1], a3 + b.y);
    c[3][2] = fminf(c[3][2], a3 + b.z); c[3][3] = fminf(c[3][3], a3 + b.w);
  }
#pragma unroll
  for (int ii = 0; ii < 4; ++ii)
#pragma unroll
    for (int jj = 0; jj < 4; ++jj)
      d[(by * 64 + i0 + ii) * NN + bx * 64 + j0 + jj] = c[ii][jj];
}

// ---------------------------------------------------------------------------
// anchors[rank] = i for rank < A, rank = #{j: nw[j]>nw[i]} + #{j<i: nw[j]==nw[i]}
// == stable argsort(-nw) positions. nw staged in LDS (broadcast reads), each
// row's scan split over 4 lanes to cut the serial chain 4x.
// ---------------------------------------------------------------------------
__global__ __launch_bounds__(256) void anchors_kernel(
    const float* __restrict__ nw, int* __restrict__ anchors) {
  __shared__ __align__(16) float s[NN];
  int t = threadIdx.x;
#pragma unroll
  for (int l = 0; l < NN / 256; ++l) s[l * 256 + t] = nw[l * 256 + t];
  __syncthreads();
  int i = blockIdx.x * 64 + (t >> 2);   // grid = 32 blocks -> i in [0,2048)
  int q = t & 3;                        // quarter of the j-range
  float wi = s[i];
  int rank = 0;
  int jb = q * (NN / 4);
  for (int j = jb; j < jb + NN / 4; j += 4) {
    float4 v = *(const float4*)&s[j];
    rank += (int)(v.x > wi) + ((int)(v.x == wi) & (int)(j + 0 < i));
    rank += (int)(v.y > wi) + ((int)(v.y == wi) & (int)(j + 1 < i));
    rank += (int)(v.z > wi) + ((int)(v.z == wi) & (int)(j + 2 < i));
    rank += (int)(v.w > wi) + ((int)(v.w == wi) & (int)(j + 3 < i));
  }
  rank += __shfl_xor(rank, 1);
  rank += __shfl_xor(rank, 2);
  if (q == 0 && rank < AA) anchors[rank] = i;
}

// ---------------------------------------------------------------------------
// Gather consensus_vectors (inf -> 100), accumulate global sum for the scalar.
// ---------------------------------------------------------------------------
__global__ __launch_bounds__(256) void cv_kernel(
    const float* __restrict__ dist, const int* __restrict__ anchors,
    float* __restrict__ cv_out, float* __restrict__ sum_acc) {
  int idx = blockIdx.x * 256 + threadIdx.x;   // 800*256 == 204800 exactly
  int i = idx / 100, a = idx - i * 100;
  float dv = dist[i * NN + anchors[a]];
  if (isinf(dv)) dv = 100.0f;
  cv_out[idx] = dv;
  float v = dv;
#pragma unroll
  for (int off = 32; off > 0; off >>= 1) v += __shfl_down(v, off);
  __shared__ float sv[4];
  int lane = threadIdx.x & 63, w = threadIdx.x >> 6;
  if (lane == 0) sv[w] = v;
  __syncthreads();
  if (threadIdx.x == 0) atomicAdd(sum_acc, sv[0] + sv[1] + sv[2] + sv[3]);
}

// ---------------------------------------------------------------------------
// consensus_graph: weighted = wm*cv computed on the fly; per-row xx computed
// in-block (identical arithmetic for i- and j-tiles); K=100 f32 dot + epilogue.
// ---------------------------------------------------------------------------
__global__ __launch_bounds__(256) void graph_kernel(
    const float* __restrict__ wm, const float* __restrict__ cv,
    const float* __restrict__ sigma, float* __restrict__ graph) {
  __shared__ __align__(16) float As[64][108];
  __shared__ __align__(16) float Bs[64][108];
  __shared__ float xs[64], ys[64];
  int bx = blockIdx.x, by = blockIdx.y;
  int t = threadIdx.x;
#pragma unroll
  for (int l = 0; l < 7; ++l) {
    int idx = l * 256 + t;
    if (idx < 1600) {                 // 64 rows * 25 float4
      int row = idx / 25, c4 = (idx - row * 25) * 4;
      float4 wa = *(const float4*)&wm[(by * 64 + row) * AA + c4];
      float4 ca = *(const float4*)&cv[(by * 64 + row) * AA + c4];
      *(float4*)&As[row][c4] =
          make_float4(wa.x * ca.x, wa.y * ca.y, wa.z * ca.z, wa.w * ca.w);
      float4 wb = *(const float4*)&wm[(bx * 64 + row) * AA + c4];
      float4 cb = *(const float4*)&cv[(bx * 64 + row) * AA + c4];
      *(float4*)&Bs[row][c4] =
          make_float4(wb.x * cb.x, wb.y * cb.y, wb.z * cb.z, wb.w * cb.w);
    }
  }
  __syncthreads();
  if (t < 64) {
    float s = 0.0f;
    for (int k4 = 0; k4 < 25; ++k4) {
      float4 q = *(const float4*)&As[t][k4 * 4];
      s += q.x * q.x + q.y * q.y + q.z * q.z + q.w * q.w;
    }
    xs[t] = s;
  } else if (t < 128) {
    int r = t - 64;
    float s = 0.0f;
    for (int k4 = 0; k4 < 25; ++k4) {
      float4 q = *(const float4*)&Bs[r][k4 * 4];
      s += q.x * q.x + q.y * q.y + q.z * q.z + q.w * q.w;
    }
    ys[r] = s;
  }
  __syncthreads();
  int tx = t & 15, ty = t >> 4;
  float acc[4][4] = {{0.0f}};
#pragma unroll 5
  for (int k4 = 0; k4 < 25; ++k4) {
    int k = k4 * 4;
    float4 a_[4], b_[4];
#pragma unroll
    for (int ii = 0; ii < 4; ++ii) a_[ii] = *(const float4*)&As[ty + 16 * ii][k];
#pragma unroll
    for (int jj = 0; jj < 4; ++jj) b_[jj] = *(const float4*)&Bs[tx + 16 * jj][k];
#pragma unroll
    for (int ii = 0; ii < 4; ++ii)
#pragma unroll
      for (int jj = 0; jj < 4; ++jj)
        acc[ii][jj] += a_[ii].x * b_[jj].x + a_[ii].y * b_[jj].y +
                       a_[ii].z * b_[jj].z + a_[ii].w * b_[jj].w;
  }
  float s = *sigma;
  float inv2s2 = 0.5f / (s * s);
#pragma unroll
  for (int ii = 0; ii < 4; ++ii) {
    int gi = by * 64 + ty + 16 * ii;
    float xi = xs[ty + 16 * ii];
#pragma unroll
    for (int jj = 0; jj < 4; ++jj) {
      int gj = bx * 64 + tx + 16 * jj;
      float sq = fmaxf(xi + ys[tx + 16 * jj] - 2.0f * acc[ii][jj], 0.0f);
      graph[gi * NN + gj] = __expf(-(sq * sq) * inv2s2);  // scalar store: base may be 4B-aligned
    }
  }
}

__global__ void finalize_kernel(const float* __restrict__ sum_acc,
                                float* __restrict__ out) {
  if (threadIdx.x == 0)
    *out = (*sum_acc - 204800.0f) / 204800.0f;  // (sum - N*100) / (N*A)
}

// ---------------------------------------------------------------------------
extern "C" void kernel_launch(void* const* d_in, const int* in_sizes, int n_in,
                              void* d_out, int out_size, void* d_ws, size_t ws_size,
                              hipStream_t stream) {
  (void)in_sizes; (void)n_in; (void)out_size;
  const float* mg    = (const float*)d_in[0];
  const float* nw    = (const float*)d_in[1];
  const float* wm    = (const float*)d_in[2];
  const float* sigma = (const float*)d_in[3];
  float* out        = (float*)d_out;
  float* cv_out     = out;            // 2048*100
  float* scalar_out = out + 204800;   // 1
  float* graph_out  = out + 204801;   // 2048*2048

  float* W = (float*)d_ws;
  float* sum_acc = W;                 // 1 float
  int* anchors   = (int*)(W + 4);     // 100 ints
  float* dist;
  if (ws_size >= (size_t)(256 + (size_t)NN * NN) * sizeof(float)) {
    dist = W + 256;                   // 16 MB scratch
  } else {
    // Fallback: alias dist onto the consensus_graph output region (4B-aligned —
    // every global access to dist is scalar b32). graph_kernel fully overwrites
    // it AFTER cv_kernel has extracted the anchor columns.
    dist = graph_out;
  }

  hipMemsetAsync(sum_acc, 0, sizeof(float), stream);
  build_w_kernel<<<dim3(NT, NT), 256, 0, stream>>>(mg, nw, dist);
  for (int r = 0; r < NT; ++r) {
    fw_p12<<<dim3(NT, 2), 256, 0, stream>>>(dist, r);
    fw_phase3<<<dim3(NT, NT), 256, 0, stream>>>(dist, r);
  }
  anchors_kernel<<<NN / 64, 256, 0, stream>>>(nw, anchors);
  cv_kernel<<<800, 256, 0, stream>>>(dist, anchors, cv_out, sum_acc);
  graph_kernel<<<dim3(NT, NT), 256, 0, stream>>>(wm, cv_out, sigma, graph_out);
  finalize_kernel<<<1, 64, 0, stream>>>(sum_acc, scalar_out);
}

// Round 3
// 2427.325 us; speedup vs baseline: 1.0522x; 1.0278x over previous
//
#include <hip/hip_runtime.h>

// Problem constants (reference: N=2048, A=100)
#define NN 2048
#define AA 100
#define NT 32   // 64-wide tiles per side (2048/64)

// ---------------------------------------------------------------------------
// Kernel 1: build w[i][j] = min(f(mg[i][j]*nw[i]), f(mg[j][i]*nw[j])), f(x)=x>0?x:inf,
// diag=0. Transpose element fetched via LDS tile to keep both reads coalesced.
// ---------------------------------------------------------------------------
__global__ __launch_bounds__(256) void build_w_kernel(
    const float* __restrict__ mg, const float* __restrict__ nw,
    float* __restrict__ w) {
  __shared__ float Tt[64][65];
  int bi = blockIdx.y, bj = blockIdx.x;
  int t = threadIdx.x;
#pragma unroll
  for (int l = 0; l < 16; ++l) {
    int idx = l * 256 + t;
    int r = idx >> 6, c = idx & 63;
    // Tt[x][y] = mg[(bj*64+y)][bi*64+x]
    Tt[c][r] = mg[(bj * 64 + r) * NN + bi * 64 + c];
  }
  __syncthreads();
#pragma unroll
  for (int l = 0; l < 16; ++l) {
    int idx = l * 256 + t;
    int r = idx >> 6, c = idx & 63;
    int i = bi * 64 + r, j = bj * 64 + c;
    float a = mg[i * NN + j] * nw[i];
    float b = Tt[r][c] * nw[j];   // = mg[j][i] * nw[j]
    float wa = a > 0.0f ? a : __builtin_huge_valf();
    float wb = b > 0.0f ? b : __builtin_huge_valf();
    float v = fminf(wa, wb);
    if (i == j) v = 0.0f;
    w[i * NN + j] = v;            // scalar store: dist may be only 4B-aligned
  }
}

// ---------------------------------------------------------------------------
// Single-wave (barrier-free) FW closure of the 64x64 tile in Ts.
// Lane j owns row j in 16 float4 registers; an LDS shadow of the tile is kept
// current by republishing the row each step. One wave64 executes in per-
// instruction lockstep: within step k, the a-read (Ts[j][k]) and the row-k
// broadcast reads happen BEFORE any lane's publish writes (program order), and
// __threadfence_block() + wave_barrier order step k's writes before step
// k+1's reads. d[.][k] / d[k][.] are stable during step k (d[k][k]=0), so
// reading the step-(k-1) values is exactly the FW recurrence.
// Bank note: row stride 68 under b128 puts exactly 8 dwords on each of the 32
// banks per instruction — iso-cost with conflict-free b128.
// On exit Ts holds the closed tile. Call with ALL threads; only t<64 works.
// ---------------------------------------------------------------------------
__device__ __forceinline__ void close_diag_wave(float (*Ts)[68], int t) {
  if (t < 64) {
    const int j = t;
    float4 R[16];
#pragma unroll
    for (int g = 0; g < 16; ++g) R[g] = *(const float4*)&Ts[j][g * 4];
    for (int k = 0; k < 64; ++k) {
      float a = Ts[j][k];                 // own-row shadow element k (current)
      const float* rowk = &Ts[k][0];      // row k (published at step k-1)
#pragma unroll
      for (int g = 0; g < 16; ++g) {
        float4 b = *(const float4*)&rowk[g * 4];
        R[g].x = fminf(R[g].x, a + b.x);
        R[g].y = fminf(R[g].y, a + b.y);
        R[g].z = fminf(R[g].z, a + b.z);
        R[g].w = fminf(R[g].w, a + b.w);
      }
#pragma unroll
      for (int g = 0; g < 16; ++g) *(float4*)&Ts[j][g * 4] = R[g];
      __threadfence_block();              // lgkmcnt drain + ordering
      __builtin_amdgcn_wave_barrier();    // pin compiler ordering
    }
  }
  __syncthreads();                        // make closed tile visible to waves 1-3
}

// ---------------------------------------------------------------------------
// Fused phase1+phase2: every block redundantly closes the diagonal tile (r,r)
// in LDS (reads the PRE-closure global values, so all blocks see identical
// input), then:
//   block (r, 0)  : stores the closed diag back to global
//   block (t, 0)  : row tile   C(r,t) = min(C, diag (x) C)    [A = closed diag]
//   block (t, 1)  : col tile   C(t,r) = min(C, C (x) diag)    [B = closed diag]
// One-pass in-place update is valid because diag is transitively closed.
// ---------------------------------------------------------------------------
__global__ __launch_bounds__(256) void fw_p12(float* __restrict__ d, int r) {
  __shared__ __align__(16) float Ts[64][68];   // diagonal tile (closed in-place)
  __shared__ __align__(16) float Us[64][68];   // this block's own tile
  int tile = blockIdx.x, side = blockIdx.y;
  if (tile == r && side == 1) return;
  int t = threadIdx.x;
  int dbase = (r * 64) * NN + r * 64;
#pragma unroll
  for (int l = 0; l < 16; ++l) {
    int idx = l * 256 + t;
    int row = idx >> 6, col = idx & 63;
    Ts[row][col] = d[dbase + row * NN + col];
  }
  int obase = 0;
  if (tile != r) {
    obase = (side == 0) ? (r * 64) * NN + tile * 64
                        : (tile * 64) * NN + r * 64;
#pragma unroll
    for (int l = 0; l < 16; ++l) {
      int idx = l * 256 + t;
      int row = idx >> 6, col = idx & 63;
      Us[row][col] = d[obase + row * NN + col];
    }
  }
  __syncthreads();
  close_diag_wave(Ts, t);   // includes trailing __syncthreads

  if (tile == r) {  // side==0: write closed diag, done
#pragma unroll
    for (int l = 0; l < 16; ++l) {
      int idx = l * 256 + t;
      int row = idx >> 6, col = idx & 63;
      d[dbase + row * NN + col] = Ts[row][col];
    }
    return;
  }

  int tx = t & 15, ty = t >> 4;
  int i0 = ty * 4, j0 = tx * 4;
  float c[4][4];
#pragma unroll
  for (int ii = 0; ii < 4; ++ii)
#pragma unroll
    for (int jj = 0; jj < 4; ++jj) c[ii][jj] = Us[i0 + ii][j0 + jj];

  float (*Ap)[68] = (side == 0) ? Ts : Us;  // A operand
  float (*Bp)[68] = (side == 0) ? Us : Ts;  // B operand
#pragma unroll 4
  for (int k = 0; k < 64; ++k) {
    float a0 = Ap[i0 + 0][k], a1 = Ap[i0 + 1][k], a2 = Ap[i0 + 2][k], a3 = Ap[i0 + 3][k];
    float4 b = *(const float4*)&Bp[k][j0];
    c[0][0] = fminf(c[0][0], a0 + b.x); c[0][1] = fminf(c[0][1], a0 + b.y);
    c[0][2] = fminf(c[0][2], a0 + b.z); c[0][3] = fminf(c[0][3], a0 + b.w);
    c[1][0] = fminf(c[1][0], a1 + b.x); c[1][1] = fminf(c[1][1], a1 + b.y);
    c[1][2] = fminf(c[1][2], a1 + b.z); c[1][3] = fminf(c[1][3], a1 + b.w);
    c[2][0] = fminf(c[2][0], a2 + b.x); c[2][1] = fminf(c[2][1], a2 + b.y);
    c[2][2] = fminf(c[2][2], a2 + b.z); c[2][3] = fminf(c[2][3], a2 + b.w);
    c[3][0] = fminf(c[3][0], a3 + b.x); c[3][1] = fminf(c[3][1], a3 + b.y);
    c[3][2] = fminf(c[3][2], a3 + b.z); c[3][3] = fminf(c[3][3], a3 + b.w);
  }
#pragma unroll
  for (int ii = 0; ii < 4; ++ii)
#pragma unroll
    for (int jj = 0; jj < 4; ++jj)
      d[obase + (i0 + ii) * NN + (j0 + jj)] = c[ii][jj];
}

// Phase 3: all remaining tiles (by,bx): C = min(C, (by,r) (x) (r,bx)).
__global__ __launch_bounds__(256) void fw_phase3(float* __restrict__ d, int r) {
  __shared__ __align__(16) float As[64][68];
  __shared__ __align__(16) float Bs[64][68];
  int bx = blockIdx.x, by = blockIdx.y;
  if (bx == r || by == r) return;
  int t = threadIdx.x;
#pragma unroll
  for (int l = 0; l < 16; ++l) {
    int idx = l * 256 + t;
    int row = idx >> 6, col = idx & 63;
    As[row][col] = d[(by * 64 + row) * NN + r * 64 + col];
    Bs[row][col] = d[(r * 64 + row) * NN + bx * 64 + col];
  }
  int tx = t & 15, ty = t >> 4;
  int i0 = ty * 4, j0 = tx * 4;
  float c[4][4];
#pragma unroll
  for (int ii = 0; ii < 4; ++ii)
#pragma unroll
    for (int jj = 0; jj < 4; ++jj)
      c[ii][jj] = d[(by * 64 + i0 + ii) * NN + bx * 64 + j0 + jj];
  __syncthreads();
#pragma unroll 4
  for (int k = 0; k < 64; ++k) {
    float a0 = As[i0 + 0][k], a1 = As[i0 + 1][k], a2 = As[i0 + 2][k], a3 = As[i0 + 3][k];
    float4 b = *(const float4*)&Bs[k][j0];
    c[0][0] = fminf(c[0][0], a0 + b.x); c[0][1] = fminf(c[0][1], a0 + b.y);
    c[0][2] = fminf(c[0][2], a0 + b.z); c[0][3] = fminf(c[0][3], a0 + b.w);
    c[1][0] = fminf(c[1][0], a1 + b.x); c[1][1] = fminf(c[1][1], a1 + b.y);
    c[1][2] = fminf(c[1][2], a1 + b.z); c[1][3] = fminf(c[1][3], a1 + b.w);
    c[2][0] = fminf(c[2][0], a2 + b.x); c[2][1] = fminf(c[2][1], a2 + b.y);
    c[2][2] = fminf(c[2][2], a2 + b.z); c[2][3] = fminf(c[2][3], a2 + b.w);
    c[3][0] = fminf(c[3][0], a3 + b.x); c[3][1] = fminf(c[3][1], a3 + b.y);
    c[3][2] = fminf(c[3][2], a3 + b.z); c[3][3] = fminf(c[3][3], a3 + b.w);
  }
#pragma unroll
  for (int ii = 0; ii < 4; ++ii)
#pragma unroll
    for (int jj = 0; jj < 4; ++jj)
      d[(by * 64 + i0 + ii) * NN + bx * 64 + j0 + jj] = c[ii][jj];
}

// ---------------------------------------------------------------------------
// anchors[rank] = i for rank < A, rank = #{j: nw[j]>nw[i]} + #{j<i: nw[j]==nw[i]}
// == stable argsort(-nw) positions. nw staged in LDS (broadcast reads), each
// row's scan split over 4 lanes to cut the serial chain 4x.
// ---------------------------------------------------------------------------
__global__ __launch_bounds__(256) void anchors_kernel(
    const float* __restrict__ nw, int* __restrict__ anchors) {
  __shared__ __align__(16) float s[NN];
  int t = threadIdx.x;
#pragma unroll
  for (int l = 0; l < NN / 256; ++l) s[l * 256 + t] = nw[l * 256 + t];
  __syncthreads();
  int i = blockIdx.x * 64 + (t >> 2);   // grid = 32 blocks -> i in [0,2048)
  int q = t & 3;                        // quarter of the j-range
  float wi = s[i];
  int rank = 0;
  int jb = q * (NN / 4);
  for (int j = jb; j < jb + NN / 4; j += 4) {
    float4 v = *(const float4*)&s[j];
    rank += (int)(v.x > wi) + ((int)(v.x == wi) & (int)(j + 0 < i));
    rank += (int)(v.y > wi) + ((int)(v.y == wi) & (int)(j + 1 < i));
    rank += (int)(v.z > wi) + ((int)(v.z == wi) & (int)(j + 2 < i));
    rank += (int)(v.w > wi) + ((int)(v.w == wi) & (int)(j + 3 < i));
  }
  rank += __shfl_xor(rank, 1);
  rank += __shfl_xor(rank, 2);
  if (q == 0 && rank < AA) anchors[rank] = i;
}

// ---------------------------------------------------------------------------
// Gather consensus_vectors (inf -> 100), accumulate global sum for the scalar.
// ---------------------------------------------------------------------------
__global__ __launch_bounds__(256) void cv_kernel(
    const float* __restrict__ dist, const int* __restrict__ anchors,
    float* __restrict__ cv_out, float* __restrict__ sum_acc) {
  int idx = blockIdx.x * 256 + threadIdx.x;   // 800*256 == 204800 exactly
  int i = idx / 100, a = idx - i * 100;
  float dv = dist[i * NN + anchors[a]];
  if (isinf(dv)) dv = 100.0f;
  cv_out[idx] = dv;
  float v = dv;
#pragma unroll
  for (int off = 32; off > 0; off >>= 1) v += __shfl_down(v, off);
  __shared__ float sv[4];
  int lane = threadIdx.x & 63, w = threadIdx.x >> 6;
  if (lane == 0) sv[w] = v;
  __syncthreads();
  if (threadIdx.x == 0) atomicAdd(sum_acc, sv[0] + sv[1] + sv[2] + sv[3]);
}

// ---------------------------------------------------------------------------
// consensus_graph: weighted = wm*cv computed on the fly; per-row xx computed
// in-block (identical arithmetic for i- and j-tiles); K=100 f32 dot + epilogue.
// ---------------------------------------------------------------------------
__global__ __launch_bounds__(256) void graph_kernel(
    const float* __restrict__ wm, const float* __restrict__ cv,
    const float* __restrict__ sigma, float* __restrict__ graph) {
  __shared__ __align__(16) float As[64][108];
  __shared__ __align__(16) float Bs[64][108];
  __shared__ float xs[64], ys[64];
  int bx = blockIdx.x, by = blockIdx.y;
  int t = threadIdx.x;
#pragma unroll
  for (int l = 0; l < 7; ++l) {
    int idx = l * 256 + t;
    if (idx < 1600) {                 // 64 rows * 25 float4
      int row = idx / 25, c4 = (idx - row * 25) * 4;
      float4 wa = *(const float4*)&wm[(by * 64 + row) * AA + c4];
      float4 ca = *(const float4*)&cv[(by * 64 + row) * AA + c4];
      *(float4*)&As[row][c4] =
          make_float4(wa.x * ca.x, wa.y * ca.y, wa.z * ca.z, wa.w * ca.w);
      float4 wb = *(const float4*)&wm[(bx * 64 + row) * AA + c4];
      float4 cb = *(const float4*)&cv[(bx * 64 + row) * AA + c4];
      *(float4*)&Bs[row][c4] =
          make_float4(wb.x * cb.x, wb.y * cb.y, wb.z * cb.z, wb.w * cb.w);
    }
  }
  __syncthreads();
  if (t < 64) {
    float s = 0.0f;
    for (int k4 = 0; k4 < 25; ++k4) {
      float4 q = *(const float4*)&As[t][k4 * 4];
      s += q.x * q.x + q.y * q.y + q.z * q.z + q.w * q.w;
    }
    xs[t] = s;
  } else if (t < 128) {
    int r = t - 64;
    float s = 0.0f;
    for (int k4 = 0; k4 < 25; ++k4) {
      float4 q = *(const float4*)&Bs[r][k4 * 4];
      s += q.x * q.x + q.y * q.y + q.z * q.z + q.w * q.w;
    }
    ys[r] = s;
  }
  __syncthreads();
  int tx = t & 15, ty = t >> 4;
  float acc[4][4] = {{0.0f}};
#pragma unroll 5
  for (int k4 = 0; k4 < 25; ++k4) {
    int k = k4 * 4;
    float4 a_[4], b_[4];
#pragma unroll
    for (int ii = 0; ii < 4; ++ii) a_[ii] = *(const float4*)&As[ty + 16 * ii][k];
#pragma unroll
    for (int jj = 0; jj < 4; ++jj) b_[jj] = *(const float4*)&Bs[tx + 16 * jj][k];
#pragma unroll
    for (int ii = 0; ii < 4; ++ii)
#pragma unroll
      for (int jj = 0; jj < 4; ++jj)
        acc[ii][jj] += a_[ii].x * b_[jj].x + a_[ii].y * b_[jj].y +
                       a_[ii].z * b_[jj].z + a_[ii].w * b_[jj].w;
  }
  float s = *sigma;
  float inv2s2 = 0.5f / (s * s);
#pragma unroll
  for (int ii = 0; ii < 4; ++ii) {
    int gi = by * 64 + ty + 16 * ii;
    float xi = xs[ty + 16 * ii];
#pragma unroll
    for (int jj = 0; jj < 4; ++jj) {
      int gj = bx * 64 + tx + 16 * jj;
      float sq = fmaxf(xi + ys[tx + 16 * jj] - 2.0f * acc[ii][jj], 0.0f);
      graph[gi * NN + gj] = __expf(-(sq * sq) * inv2s2);  // scalar store: base may be 4B-aligned
    }
  }
}

__global__ void finalize_kernel(const float* __restrict__ sum_acc,
                                float* __restrict__ out) {
  if (threadIdx.x == 0)
    *out = (*sum_acc - 204800.0f) / 204800.0f;  // (sum - N*100) / (N*A)
}

// ---------------------------------------------------------------------------
extern "C" void kernel_launch(void* const* d_in, const int* in_sizes, int n_in,
                              void* d_out, int out_size, void* d_ws, size_t ws_size,
                              hipStream_t stream) {
  (void)in_sizes; (void)n_in; (void)out_size;
  const float* mg    = (const float*)d_in[0];
  const float* nw    = (const float*)d_in[1];
  const float* wm    = (const float*)d_in[2];
  const float* sigma = (const float*)d_in[3];
  float* out        = (float*)d_out;
  float* cv_out     = out;            // 2048*100
  float* scalar_out = out + 204800;   // 1
  float* graph_out  = out + 204801;   // 2048*2048

  float* W = (float*)d_ws;
  float* sum_acc = W;                 // 1 float
  int* anchors   = (int*)(W + 4);     // 100 ints
  float* dist;
  if (ws_size >= (size_t)(256 + (size_t)NN * NN) * sizeof(float)) {
    dist = W + 256;                   // 16 MB scratch
  } else {
    // Fallback: alias dist onto the consensus_graph output region (4B-aligned —
    // every global access to dist is scalar b32). graph_kernel fully overwrites
    // it AFTER cv_kernel has extracted the anchor columns.
    dist = graph_out;
  }

  hipMemsetAsync(sum_acc, 0, sizeof(float), stream);
  build_w_kernel<<<dim3(NT, NT), 256, 0, stream>>>(mg, nw, dist);
  for (int r = 0; r < NT; ++r) {
    fw_p12<<<dim3(NT, 2), 256, 0, stream>>>(dist, r);
    fw_phase3<<<dim3(NT, NT), 256, 0, stream>>>(dist, r);
  }
  anchors_kernel<<<NN / 64, 256, 0, stream>>>(nw, anchors);
  cv_kernel<<<800, 256, 0, stream>>>(dist, anchors, cv_out, sum_acc);
  graph_kernel<<<dim3(NT, NT), 256, 0, stream>>>(wm, cv_out, sigma, graph_out);
  finalize_kernel<<<1, 64, 0, stream>>>(sum_acc, scalar_out);
}

// Round 4
// 1452.676 us; speedup vs baseline: 1.7581x; 1.6709x over previous
//
#include <hip/hip_runtime.h>

// Problem constants (reference: N=2048, A=100)
#define NN 2048
#define AA 100
#define NT 32   // 64-wide tiles per side (2048/64)

// ---------------------------------------------------------------------------
// Kernel 1: build w[i][j] = min(f(mg[i][j]*nw[i]), f(mg[j][i]*nw[j])), f(x)=x>0?x:inf,
// diag=0. Transpose element fetched via LDS tile to keep both reads coalesced.
// ---------------------------------------------------------------------------
__global__ __launch_bounds__(256) void build_w_kernel(
    const float* __restrict__ mg, const float* __restrict__ nw,
    float* __restrict__ w) {
  __shared__ float Tt[64][65];
  int bi = blockIdx.y, bj = blockIdx.x;
  int t = threadIdx.x;
#pragma unroll
  for (int l = 0; l < 16; ++l) {
    int idx = l * 256 + t;
    int r = idx >> 6, c = idx & 63;
    // Tt[x][y] = mg[(bj*64+y)][bi*64+x]
    Tt[c][r] = mg[(bj * 64 + r) * NN + bi * 64 + c];
  }
  __syncthreads();
#pragma unroll
  for (int l = 0; l < 16; ++l) {
    int idx = l * 256 + t;
    int r = idx >> 6, c = idx & 63;
    int i = bi * 64 + r, j = bj * 64 + c;
    float a = mg[i * NN + j] * nw[i];
    float b = Tt[r][c] * nw[j];   // = mg[j][i] * nw[j]
    float wa = a > 0.0f ? a : __builtin_huge_valf();
    float wb = b > 0.0f ? b : __builtin_huge_valf();
    float v = fminf(wa, wb);
    if (i == j) v = 0.0f;
    w[i * NN + j] = v;            // scalar store: dist may be only 4B-aligned
  }
}

// ---------------------------------------------------------------------------
// One min-plus squaring step: dst = src (x) src  (elementwise over the 64x64
// tile; the k==i term contributes src[i][j] since src[i][i]==0, so dst <= src).
// Fully parallel: 256 threads, 4x4 register micro-tile, 1 barrier at the end.
// Six applications == in-tile FW transitive closure (paths up to 64 edges).
// ---------------------------------------------------------------------------
__device__ __forceinline__ void square_step(const float (*src)[68], float (*dst)[68]) {
  int t = threadIdx.x;
  int tx = t & 15, ty = t >> 4;
  int i0 = ty * 4, j0 = tx * 4;
  float c[4][4];
#pragma unroll
  for (int ii = 0; ii < 4; ++ii)
#pragma unroll
    for (int jj = 0; jj < 4; ++jj) c[ii][jj] = src[i0 + ii][j0 + jj];
#pragma unroll 4
  for (int k = 0; k < 64; ++k) {
    float a0 = src[i0 + 0][k], a1 = src[i0 + 1][k], a2 = src[i0 + 2][k], a3 = src[i0 + 3][k];
    float4 b = *(const float4*)&src[k][j0];
    c[0][0] = fminf(c[0][0], a0 + b.x); c[0][1] = fminf(c[0][1], a0 + b.y);
    c[0][2] = fminf(c[0][2], a0 + b.z); c[0][3] = fminf(c[0][3], a0 + b.w);
    c[1][0] = fminf(c[1][0], a1 + b.x); c[1][1] = fminf(c[1][1], a1 + b.y);
    c[1][2] = fminf(c[1][2], a1 + b.z); c[1][3] = fminf(c[1][3], a1 + b.w);
    c[2][0] = fminf(c[2][0], a2 + b.x); c[2][1] = fminf(c[2][1], a2 + b.y);
    c[2][2] = fminf(c[2][2], a2 + b.z); c[2][3] = fminf(c[2][3], a2 + b.w);
    c[3][0] = fminf(c[3][0], a3 + b.x); c[3][1] = fminf(c[3][1], a3 + b.y);
    c[3][2] = fminf(c[3][2], a3 + b.z); c[3][3] = fminf(c[3][3], a3 + b.w);
  }
#pragma unroll
  for (int ii = 0; ii < 4; ++ii)
    *(float4*)&dst[i0 + ii][j0] = make_float4(c[ii][0], c[ii][1], c[ii][2], c[ii][3]);
  __syncthreads();
}

// Standalone closure of tile (0,0) — runs once before round 0.
__global__ __launch_bounds__(256) void fw_close0(float* __restrict__ d) {
  __shared__ __align__(16) float As[64][68];
  __shared__ __align__(16) float Bs[64][68];
  int t = threadIdx.x;
#pragma unroll
  for (int l = 0; l < 16; ++l) {
    int idx = l * 256 + t;
    int row = idx >> 6, col = idx & 63;
    As[row][col] = d[row * NN + col];
  }
  __syncthreads();
  square_step(As, Bs); square_step(Bs, As);
  square_step(As, Bs); square_step(Bs, As);
  square_step(As, Bs); square_step(Bs, As);   // closed tile in As
#pragma unroll
  for (int l = 0; l < 16; ++l) {
    int idx = l * 256 + t;
    int row = idx >> 6, col = idx & 63;
    d[row * NN + col] = As[row][col];
  }
}

// ---------------------------------------------------------------------------
// Phase 2 (diag tile ALREADY closed in global, by fw_close0 / previous round's
// fw_p3 designated block):
//   block (t, 0)  : row tile   C(r,t) = min(C, diag (x) C)
//   block (t, 1)  : col tile   C(t,r) = min(C, C (x) diag)
// One-pass in-place update is valid because diag is transitively closed.
// ---------------------------------------------------------------------------
__global__ __launch_bounds__(256) void fw_p2(float* __restrict__ d, int r) {
  __shared__ __align__(16) float Ts[64][68];   // closed diagonal tile
  __shared__ __align__(16) float Us[64][68];   // this block's own tile
  int tile = blockIdx.x, side = blockIdx.y;
  if (tile == r) return;
  int t = threadIdx.x;
  int dbase = (r * 64) * NN + r * 64;
  int obase = (side == 0) ? (r * 64) * NN + tile * 64
                          : (tile * 64) * NN + r * 64;
#pragma unroll
  for (int l = 0; l < 16; ++l) {
    int idx = l * 256 + t;
    int row = idx >> 6, col = idx & 63;
    Ts[row][col] = d[dbase + row * NN + col];
    Us[row][col] = d[obase + row * NN + col];
  }
  __syncthreads();

  int tx = t & 15, ty = t >> 4;
  int i0 = ty * 4, j0 = tx * 4;
  float c[4][4];
#pragma unroll
  for (int ii = 0; ii < 4; ++ii)
#pragma unroll
    for (int jj = 0; jj < 4; ++jj) c[ii][jj] = Us[i0 + ii][j0 + jj];

  float (*Ap)[68] = (side == 0) ? Ts : Us;  // A operand
  float (*Bp)[68] = (side == 0) ? Us : Ts;  // B operand
#pragma unroll 4
  for (int k = 0; k < 64; ++k) {
    float a0 = Ap[i0 + 0][k], a1 = Ap[i0 + 1][k], a2 = Ap[i0 + 2][k], a3 = Ap[i0 + 3][k];
    float4 b = *(const float4*)&Bp[k][j0];
    c[0][0] = fminf(c[0][0], a0 + b.x); c[0][1] = fminf(c[0][1], a0 + b.y);
    c[0][2] = fminf(c[0][2], a0 + b.z); c[0][3] = fminf(c[0][3], a0 + b.w);
    c[1][0] = fminf(c[1][0], a1 + b.x); c[1][1] = fminf(c[1][1], a1 + b.y);
    c[1][2] = fminf(c[1][2], a1 + b.z); c[1][3] = fminf(c[1][3], a1 + b.w);
    c[2][0] = fminf(c[2][0], a2 + b.x); c[2][1] = fminf(c[2][1], a2 + b.y);
    c[2][2] = fminf(c[2][2], a2 + b.z); c[2][3] = fminf(c[2][3], a2 + b.w);
    c[3][0] = fminf(c[3][0], a3 + b.x); c[3][1] = fminf(c[3][1], a3 + b.y);
    c[3][2] = fminf(c[3][2], a3 + b.z); c[3][3] = fminf(c[3][3], a3 + b.w);
  }
#pragma unroll
  for (int ii = 0; ii < 4; ++ii)
#pragma unroll
    for (int jj = 0; jj < 4; ++jj)
      d[obase + (i0 + ii) * NN + (j0 + jj)] = c[ii][jj];
}

// ---------------------------------------------------------------------------
// Phase 3 (+ hidden closure of next round's diagonal):
//   all tiles (by,bx) off the round-r cross: C = min(C, (by,r) (x) (r,bx)).
//   The block owning (r+1,r+1) additionally closes its updated tile in LDS
//   (6 min-plus squarings) and stores the CLOSED tile — so the next round's
//   fw_p2 just loads it, and no serial closure ever sits in its own kernel.
// ---------------------------------------------------------------------------
__global__ __launch_bounds__(256) void fw_p3(float* __restrict__ d, int r) {
  __shared__ __align__(16) float As[64][68];
  __shared__ __align__(16) float Bs[64][68];
  int bx = blockIdx.x, by = blockIdx.y;
  if (bx == r || by == r) return;
  int t = threadIdx.x;
#pragma unroll
  for (int l = 0; l < 16; ++l) {
    int idx = l * 256 + t;
    int row = idx >> 6, col = idx & 63;
    As[row][col] = d[(by * 64 + row) * NN + r * 64 + col];
    Bs[row][col] = d[(r * 64 + row) * NN + bx * 64 + col];
  }
  int tx = t & 15, ty = t >> 4;
  int i0 = ty * 4, j0 = tx * 4;
  int obase = (by * 64) * NN + bx * 64;
  float c[4][4];
#pragma unroll
  for (int ii = 0; ii < 4; ++ii)
#pragma unroll
    for (int jj = 0; jj < 4; ++jj)
      c[ii][jj] = d[obase + (i0 + ii) * NN + (j0 + jj)];
  __syncthreads();
#pragma unroll 4
  for (int k = 0; k < 64; ++k) {
    float a0 = As[i0 + 0][k], a1 = As[i0 + 1][k], a2 = As[i0 + 2][k], a3 = As[i0 + 3][k];
    float4 b = *(const float4*)&Bs[k][j0];
    c[0][0] = fminf(c[0][0], a0 + b.x); c[0][1] = fminf(c[0][1], a0 + b.y);
    c[0][2] = fminf(c[0][2], a0 + b.z); c[0][3] = fminf(c[0][3], a0 + b.w);
    c[1][0] = fminf(c[1][0], a1 + b.x); c[1][1] = fminf(c[1][1], a1 + b.y);
    c[1][2] = fminf(c[1][2], a1 + b.z); c[1][3] = fminf(c[1][3], a1 + b.w);
    c[2][0] = fminf(c[2][0], a2 + b.x); c[2][1] = fminf(c[2][1], a2 + b.y);
    c[2][2] = fminf(c[2][2], a2 + b.z); c[2][3] = fminf(c[2][3], a2 + b.w);
    c[3][0] = fminf(c[3][0], a3 + b.x); c[3][1] = fminf(c[3][1], a3 + b.y);
    c[3][2] = fminf(c[3][2], a3 + b.z); c[3][3] = fminf(c[3][3], a3 + b.w);
  }

  bool closer = (bx == r + 1) && (by == r + 1) && (r + 1 < NT);
  if (!closer) {
#pragma unroll
    for (int ii = 0; ii < 4; ++ii)
#pragma unroll
      for (int jj = 0; jj < 4; ++jj)
        d[obase + (i0 + ii) * NN + (j0 + jj)] = c[ii][jj];
    return;
  }
  // Close the next diagonal tile in LDS before storing.
  __syncthreads();   // all As/Bs reads done
#pragma unroll
  for (int ii = 0; ii < 4; ++ii)
    *(float4*)&As[i0 + ii][j0] = make_float4(c[ii][0], c[ii][1], c[ii][2], c[ii][3]);
  __syncthreads();
  square_step(As, Bs); square_step(Bs, As);
  square_step(As, Bs); square_step(Bs, As);
  square_step(As, Bs); square_step(Bs, As);   // closed tile in As
#pragma unroll
  for (int l = 0; l < 16; ++l) {
    int idx = l * 256 + t;
    int row = idx >> 6, col = idx & 63;
    d[obase + row * NN + col] = As[row][col];
  }
}

// ---------------------------------------------------------------------------
// anchors[rank] = i for rank < A, rank = #{j: nw[j]>nw[i]} + #{j<i: nw[j]==nw[i]}
// == stable argsort(-nw) positions. nw staged in LDS (broadcast reads), each
// row's scan split over 4 lanes to cut the serial chain 4x.
// ---------------------------------------------------------------------------
__global__ __launch_bounds__(256) void anchors_kernel(
    const float* __restrict__ nw, int* __restrict__ anchors) {
  __shared__ __align__(16) float s[NN];
  int t = threadIdx.x;
#pragma unroll
  for (int l = 0; l < NN / 256; ++l) s[l * 256 + t] = nw[l * 256 + t];
  __syncthreads();
  int i = blockIdx.x * 64 + (t >> 2);   // grid = 32 blocks -> i in [0,2048)
  int q = t & 3;                        // quarter of the j-range
  float wi = s[i];
  int rank = 0;
  int jb = q * (NN / 4);
  for (int j = jb; j < jb + NN / 4; j += 4) {
    float4 v = *(const float4*)&s[j];
    rank += (int)(v.x > wi) + ((int)(v.x == wi) & (int)(j + 0 < i));
    rank += (int)(v.y > wi) + ((int)(v.y == wi) & (int)(j + 1 < i));
    rank += (int)(v.z > wi) + ((int)(v.z == wi) & (int)(j + 2 < i));
    rank += (int)(v.w > wi) + ((int)(v.w == wi) & (int)(j + 3 < i));
  }
  rank += __shfl_xor(rank, 1);
  rank += __shfl_xor(rank, 2);
  if (q == 0 && rank < AA) anchors[rank] = i;
}

// ---------------------------------------------------------------------------
// Gather consensus_vectors (inf -> 100), accumulate global sum for the scalar.
// ---------------------------------------------------------------------------
__global__ __launch_bounds__(256) void cv_kernel(
    const float* __restrict__ dist, const int* __restrict__ anchors,
    float* __restrict__ cv_out, float* __restrict__ sum_acc) {
  int idx = blockIdx.x * 256 + threadIdx.x;   // 800*256 == 204800 exactly
  int i = idx / 100, a = idx - i * 100;
  float dv = dist[i * NN + anchors[a]];
  if (isinf(dv)) dv = 100.0f;
  cv_out[idx] = dv;
  float v = dv;
#pragma unroll
  for (int off = 32; off > 0; off >>= 1) v += __shfl_down(v, off);
  __shared__ float sv[4];
  int lane = threadIdx.x & 63, w = threadIdx.x >> 6;
  if (lane == 0) sv[w] = v;
  __syncthreads();
  if (threadIdx.x == 0) atomicAdd(sum_acc, sv[0] + sv[1] + sv[2] + sv[3]);
}

// ---------------------------------------------------------------------------
// consensus_graph: weighted = wm*cv computed on the fly; per-row xx computed
// in-block (identical arithmetic for i- and j-tiles); K=100 f32 dot + epilogue.
// ---------------------------------------------------------------------------
__global__ __launch_bounds__(256) void graph_kernel(
    const float* __restrict__ wm, const float* __restrict__ cv,
    const float* __restrict__ sigma, float* __restrict__ graph) {
  __shared__ __align__(16) float As[64][108];
  __shared__ __align__(16) float Bs[64][108];
  __shared__ float xs[64], ys[64];
  int bx = blockIdx.x, by = blockIdx.y;
  int t = threadIdx.x;
#pragma unroll
  for (int l = 0; l < 7; ++l) {
    int idx = l * 256 + t;
    if (idx < 1600) {                 // 64 rows * 25 float4
      int row = idx / 25, c4 = (idx - row * 25) * 4;
      float4 wa = *(const float4*)&wm[(by * 64 + row) * AA + c4];
      float4 ca = *(const float4*)&cv[(by * 64 + row) * AA + c4];
      *(float4*)&As[row][c4] =
          make_float4(wa.x * ca.x, wa.y * ca.y, wa.z * ca.z, wa.w * ca.w);
      float4 wb = *(const float4*)&wm[(bx * 64 + row) * AA + c4];
      float4 cb = *(const float4*)&cv[(bx * 64 + row) * AA + c4];
      *(float4*)&Bs[row][c4] =
          make_float4(wb.x * cb.x, wb.y * cb.y, wb.z * cb.z, wb.w * cb.w);
    }
  }
  __syncthreads();
  if (t < 64) {
    float s = 0.0f;
    for (int k4 = 0; k4 < 25; ++k4) {
      float4 q = *(const float4*)&As[t][k4 * 4];
      s += q.x * q.x + q.y * q.y + q.z * q.z + q.w * q.w;
    }
    xs[t] = s;
  } else if (t < 128) {
    int r = t - 64;
    float s = 0.0f;
    for (int k4 = 0; k4 < 25; ++k4) {
      float4 q = *(const float4*)&Bs[r][k4 * 4];
      s += q.x * q.x + q.y * q.y + q.z * q.z + q.w * q.w;
    }
    ys[r] = s;
  }
  __syncthreads();
  int tx = t & 15, ty = t >> 4;
  float acc[4][4] = {{0.0f}};
#pragma unroll 5
  for (int k4 = 0; k4 < 25; ++k4) {
    int k = k4 * 4;
    float4 a_[4], b_[4];
#pragma unroll
    for (int ii = 0; ii < 4; ++ii) a_[ii] = *(const float4*)&As[ty + 16 * ii][k];
#pragma unroll
    for (int jj = 0; jj < 4; ++jj) b_[jj] = *(const float4*)&Bs[tx + 16 * jj][k];
#pragma unroll
    for (int ii = 0; ii < 4; ++ii)
#pragma unroll
      for (int jj = 0; jj < 4; ++jj)
        acc[ii][jj] += a_[ii].x * b_[jj].x + a_[ii].y * b_[jj].y +
                       a_[ii].z * b_[jj].z + a_[ii].w * b_[jj].w;
  }
  float s = *sigma;
  float inv2s2 = 0.5f / (s * s);
#pragma unroll
  for (int ii = 0; ii < 4; ++ii) {
    int gi = by * 64 + ty + 16 * ii;
    float xi = xs[ty + 16 * ii];
#pragma unroll
    for (int jj = 0; jj < 4; ++jj) {
      int gj = bx * 64 + tx + 16 * jj;
      float sq = fmaxf(xi + ys[tx + 16 * jj] - 2.0f * acc[ii][jj], 0.0f);
      graph[gi * NN + gj] = __expf(-(sq * sq) * inv2s2);  // scalar store: base may be 4B-aligned
    }
  }
}

__global__ void finalize_kernel(const float* __restrict__ sum_acc,
                                float* __restrict__ out) {
  if (threadIdx.x == 0)
    *out = (*sum_acc - 204800.0f) / 204800.0f;  // (sum - N*100) / (N*A)
}

// ---------------------------------------------------------------------------
extern "C" void kernel_launch(void* const* d_in, const int* in_sizes, int n_in,
                              void* d_out, int out_size, void* d_ws, size_t ws_size,
                              hipStream_t stream) {
  (void)in_sizes; (void)n_in; (void)out_size;
  const float* mg    = (const float*)d_in[0];
  const float* nw    = (const float*)d_in[1];
  const float* wm    = (const float*)d_in[2];
  const float* sigma = (const float*)d_in[3];
  float* out        = (float*)d_out;
  float* cv_out     = out;            // 2048*100
  float* scalar_out = out + 204800;   // 1
  float* graph_out  = out + 204801;   // 2048*2048

  float* W = (float*)d_ws;
  float* sum_acc = W;                 // 1 float
  int* anchors   = (int*)(W + 4);     // 100 ints
  float* dist;
  if (ws_size >= (size_t)(256 + (size_t)NN * NN) * sizeof(float)) {
    dist = W + 256;                   // 16 MB scratch
  } else {
    // Fallback: alias dist onto the consensus_graph output region (4B-aligned —
    // every global access to dist is scalar b32). graph_kernel fully overwrites
    // it AFTER cv_kernel has extracted the anchor columns.
    dist = graph_out;
  }

  hipMemsetAsync(sum_acc, 0, sizeof(float), stream);
  build_w_kernel<<<dim3(NT, NT), 256, 0, stream>>>(mg, nw, dist);
  fw_close0<<<1, 256, 0, stream>>>(dist);
  for (int r = 0; r < NT; ++r) {
    fw_p2<<<dim3(NT, 2), 256, 0, stream>>>(dist, r);
    fw_p3<<<dim3(NT, NT), 256, 0, stream>>>(dist, r);
  }
  anchors_kernel<<<NN / 64, 256, 0, stream>>>(nw, anchors);
  cv_kernel<<<800, 256, 0, stream>>>(dist, anchors, cv_out, sum_acc);
  graph_kernel<<<dim3(NT, NT), 256, 0, stream>>>(wm, cv_out, sigma, graph_out);
  finalize_kernel<<<1, 64, 0, stream>>>(sum_acc, scalar_out);
}

// Round 5
// 1439.211 us; speedup vs baseline: 1.7745x; 1.0094x over previous
//
#include <hip/hip_runtime.h>

// Problem constants (reference: N=2048, A=100)
#define NN 2048
#define AA 100
#define NT 32   // 64-wide tiles per side (2048/64)

// ---------------------------------------------------------------------------
// Kernel 1: build w[i][j] = min(f(mg[i][j]*nw[i]), f(mg[j][i]*nw[j])), f(x)=x>0?x:inf,
// diag=0. Transpose element fetched via LDS tile to keep both reads coalesced.
// ---------------------------------------------------------------------------
__global__ __launch_bounds__(256) void build_w_kernel(
    const float* __restrict__ mg, const float* __restrict__ nw,
    float* __restrict__ w) {
  __shared__ float Tt[64][65];
  int bi = blockIdx.y, bj = blockIdx.x;
  int t = threadIdx.x;
#pragma unroll
  for (int l = 0; l < 16; ++l) {
    int idx = l * 256 + t;
    int r = idx >> 6, c = idx & 63;
    Tt[c][r] = mg[(bj * 64 + r) * NN + bi * 64 + c];
  }
  __syncthreads();
#pragma unroll
  for (int l = 0; l < 16; ++l) {
    int idx = l * 256 + t;
    int r = idx >> 6, c = idx & 63;
    int i = bi * 64 + r, j = bj * 64 + c;
    float a = mg[i * NN + j] * nw[i];
    float b = Tt[r][c] * nw[j];   // = mg[j][i] * nw[j]
    float wa = a > 0.0f ? a : __builtin_huge_valf();
    float wb = b > 0.0f ? b : __builtin_huge_valf();
    float v = fminf(wa, wb);
    if (i == j) v = 0.0f;
    w[i * NN + j] = v;
  }
}

// ---------------------------------------------------------------------------
// k4 min-plus inner loop: c[4][4] = min(c, A(i0-rows) (x) B(j0-cols)), k=0..63.
// All LDS reads are b128 (2 per k per thread): a-rows as float4 over k-chunks,
// b-rows as float4 over j. ~35% less LDS-pipe than the scalar-a version.
// ---------------------------------------------------------------------------
__device__ __forceinline__ void minplus16(const float (*A)[68], const float (*B)[68],
                                          float c[4][4], int i0, int j0) {
#pragma unroll 4
  for (int k4 = 0; k4 < 16; ++k4) {
    const int k = k4 * 4;
    float4 a0 = *(const float4*)&A[i0 + 0][k];
    float4 a1 = *(const float4*)&A[i0 + 1][k];
    float4 a2 = *(const float4*)&A[i0 + 2][k];
    float4 a3 = *(const float4*)&A[i0 + 3][k];
    float4 b0 = *(const float4*)&B[k + 0][j0];
    float4 b1 = *(const float4*)&B[k + 1][j0];
    float4 b2 = *(const float4*)&B[k + 2][j0];
    float4 b3 = *(const float4*)&B[k + 3][j0];
#define MP_ROW(ii)                                                                        \
    c[ii][0] = fminf(c[ii][0], fminf(fminf(a##ii.x + b0.x, a##ii.y + b1.x),               \
                                     fminf(a##ii.z + b2.x, a##ii.w + b3.x)));             \
    c[ii][1] = fminf(c[ii][1], fminf(fminf(a##ii.x + b0.y, a##ii.y + b1.y),               \
                                     fminf(a##ii.z + b2.y, a##ii.w + b3.y)));             \
    c[ii][2] = fminf(c[ii][2], fminf(fminf(a##ii.x + b0.z, a##ii.y + b1.z),               \
                                     fminf(a##ii.z + b2.z, a##ii.w + b3.z)));             \
    c[ii][3] = fminf(c[ii][3], fminf(fminf(a##ii.x + b0.w, a##ii.y + b1.w),               \
                                     fminf(a##ii.z + b2.w, a##ii.w + b3.w)))
    MP_ROW(0); MP_ROW(1); MP_ROW(2); MP_ROW(3);
#undef MP_ROW
  }
}

// ---------------------------------------------------------------------------
// In-place transitive closure of the 64x64 tile in S. Thread owns c[4][4] =
// S's (i0,j0) block (caller guarantees c == S there, staged & barriered).
// 6 in-place min-plus squaring passes: values only DECREASE and every entry
// is always the length of a real path, so mid-pass read/write races are safe
// (4B LDS atomicity); each pass still dominates one strict squaring, so 6
// passes == closure (paths up to 64 edges). One barrier per pass.
// ---------------------------------------------------------------------------
__device__ __forceinline__ void close_in_lds(float (*S)[68], float c[4][4],
                                             int i0, int j0) {
  for (int p = 0; p < 6; ++p) {
    minplus16(S, S, c, i0, j0);
#pragma unroll
    for (int ii = 0; ii < 4; ++ii)
      *(float4*)&S[i0 + ii][j0] = make_float4(c[ii][0], c[ii][1], c[ii][2], c[ii][3]);
    __syncthreads();
  }
}

// Standalone closure of tile (0,0) — runs once before round 0.
__global__ __launch_bounds__(256) void fw_close0(float* __restrict__ d) {
  __shared__ __align__(16) float As[64][68];
  int t = threadIdx.x;
#pragma unroll
  for (int l = 0; l < 16; ++l) {
    int idx = l * 256 + t;
    int row = idx >> 6, col = idx & 63;
    As[row][col] = d[row * NN + col];
  }
  __syncthreads();
  int tx = t & 15, ty = t >> 4;
  int i0 = ty * 4, j0 = tx * 4;
  float c[4][4];
#pragma unroll
  for (int ii = 0; ii < 4; ++ii)
#pragma unroll
    for (int jj = 0; jj < 4; ++jj) c[ii][jj] = As[i0 + ii][j0 + jj];
  close_in_lds(As, c, i0, j0);
#pragma unroll
  for (int ii = 0; ii < 4; ++ii)
#pragma unroll
    for (int jj = 0; jj < 4; ++jj)
      d[(i0 + ii) * NN + (j0 + jj)] = c[ii][jj];
}

// ---------------------------------------------------------------------------
// Phase 2 (diag tile ALREADY closed in global):
//   block (t, 0)  : row tile   C(r,t) = min(C, diag (x) C)
//   block (t, 1)  : col tile   C(t,r) = min(C, C (x) diag)
// One-pass in-place update is valid because diag is transitively closed.
// ---------------------------------------------------------------------------
__global__ __launch_bounds__(256) void fw_p2(float* __restrict__ d, int r) {
  __shared__ __align__(16) float As[64][68];
  __shared__ __align__(16) float Bs[64][68];
  int tile = blockIdx.x, side = blockIdx.y;
  if (tile == r) return;
  int t = threadIdx.x;
  int dbase = (r * 64) * NN + r * 64;
  int obase = (side == 0) ? (r * 64) * NN + tile * 64
                          : (tile * 64) * NN + r * 64;
  // side 0: A-operand = diag, B-operand = own.  side 1: A = own, B = diag.
  float (*Da)[68] = (side == 0) ? As : Bs;   // diag staged here
  float (*Ow)[68] = (side == 0) ? Bs : As;   // own staged here
#pragma unroll
  for (int l = 0; l < 16; ++l) {
    int idx = l * 256 + t;
    int row = idx >> 6, col = idx & 63;
    Da[row][col] = d[dbase + row * NN + col];
    Ow[row][col] = d[obase + row * NN + col];
  }
  int tx = t & 15, ty = t >> 4;
  int i0 = ty * 4, j0 = tx * 4;
  float c[4][4];
#pragma unroll
  for (int ii = 0; ii < 4; ++ii)
#pragma unroll
    for (int jj = 0; jj < 4; ++jj)
      c[ii][jj] = d[obase + (i0 + ii) * NN + (j0 + jj)];
  __syncthreads();
  minplus16(As, Bs, c, i0, j0);
#pragma unroll
  for (int ii = 0; ii < 4; ++ii)
#pragma unroll
    for (int jj = 0; jj < 4; ++jj)
      d[obase + (i0 + ii) * NN + (j0 + jj)] = c[ii][jj];
}

// ---------------------------------------------------------------------------
// Phase 3 (+ fused closure of next round's diagonal):
//   tiles (by,bx) off the round-r cross: C = min(C, (by,r) (x) (r,bx)).
//   The block owning (r+1,r+1) then closes its tile in LDS (6 in-place
//   passes) and stores the CLOSED tile for the next round's fw_p2.
// ---------------------------------------------------------------------------
__global__ __launch_bounds__(256) void fw_p3(float* __restrict__ d, int r) {
  __shared__ __align__(16) float As[64][68];
  __shared__ __align__(16) float Bs[64][68];
  int bx = blockIdx.x, by = blockIdx.y;
  if (bx == r || by == r) return;
  int t = threadIdx.x;
#pragma unroll
  for (int l = 0; l < 16; ++l) {
    int idx = l * 256 + t;
    int row = idx >> 6, col = idx & 63;
    As[row][col] = d[(by * 64 + row) * NN + r * 64 + col];
    Bs[row][col] = d[(r * 64 + row) * NN + bx * 64 + col];
  }
  int tx = t & 15, ty = t >> 4;
  int i0 = ty * 4, j0 = tx * 4;
  int obase = (by * 64) * NN + bx * 64;
  float c[4][4];
#pragma unroll
  for (int ii = 0; ii < 4; ++ii)
#pragma unroll
    for (int jj = 0; jj < 4; ++jj)
      c[ii][jj] = d[obase + (i0 + ii) * NN + (j0 + jj)];
  __syncthreads();
  minplus16(As, Bs, c, i0, j0);

  bool closer = (bx == r + 1) && (by == r + 1) && (r + 1 < NT);
  if (closer) {
    __syncthreads();   // all As/Bs reads of the minplus done
#pragma unroll
    for (int ii = 0; ii < 4; ++ii)
      *(float4*)&As[i0 + ii][j0] = make_float4(c[ii][0], c[ii][1], c[ii][2], c[ii][3]);
    __syncthreads();
    close_in_lds(As, c, i0, j0);
  }
#pragma unroll
  for (int ii = 0; ii < 4; ++ii)
#pragma unroll
    for (int jj = 0; jj < 4; ++jj)
      d[obase + (i0 + ii) * NN + (j0 + jj)] = c[ii][jj];
}

// ---------------------------------------------------------------------------
// anchors[rank] = i for rank < A, rank = #{j: nw[j]>nw[i]} + #{j<i: nw[j]==nw[i]}
// == stable argsort(-nw) positions. nw staged in LDS, row scan split 4 ways.
// ---------------------------------------------------------------------------
__global__ __launch_bounds__(256) void anchors_kernel(
    const float* __restrict__ nw, int* __restrict__ anchors) {
  __shared__ __align__(16) float s[NN];
  int t = threadIdx.x;
#pragma unroll
  for (int l = 0; l < NN / 256; ++l) s[l * 256 + t] = nw[l * 256 + t];
  __syncthreads();
  int i = blockIdx.x * 64 + (t >> 2);
  int q = t & 3;
  float wi = s[i];
  int rank = 0;
  int jb = q * (NN / 4);
  for (int j = jb; j < jb + NN / 4; j += 4) {
    float4 v = *(const float4*)&s[j];
    rank += (int)(v.x > wi) + ((int)(v.x == wi) & (int)(j + 0 < i));
    rank += (int)(v.y > wi) + ((int)(v.y == wi) & (int)(j + 1 < i));
    rank += (int)(v.z > wi) + ((int)(v.z == wi) & (int)(j + 2 < i));
    rank += (int)(v.w > wi) + ((int)(v.w == wi) & (int)(j + 3 < i));
  }
  rank += __shfl_xor(rank, 1);
  rank += __shfl_xor(rank, 2);
  if (q == 0 && rank < AA) anchors[rank] = i;
}

// ---------------------------------------------------------------------------
// Gather consensus_vectors (inf -> 100), accumulate global sum for the scalar.
// ---------------------------------------------------------------------------
__global__ __launch_bounds__(256) void cv_kernel(
    const float* __restrict__ dist, const int* __restrict__ anchors,
    float* __restrict__ cv_out, float* __restrict__ sum_acc) {
  int idx = blockIdx.x * 256 + threadIdx.x;   // 800*256 == 204800 exactly
  int i = idx / 100, a = idx - i * 100;
  float dv = dist[i * NN + anchors[a]];
  if (isinf(dv)) dv = 100.0f;
  cv_out[idx] = dv;
  float v = dv;
#pragma unroll
  for (int off = 32; off > 0; off >>= 1) v += __shfl_down(v, off);
  __shared__ float sv[4];
  int lane = threadIdx.x & 63, w = threadIdx.x >> 6;
  if (lane == 0) sv[w] = v;
  __syncthreads();
  if (threadIdx.x == 0) atomicAdd(sum_acc, sv[0] + sv[1] + sv[2] + sv[3]);
}

// ---------------------------------------------------------------------------
// consensus_graph: weighted = wm*cv on the fly; per-row xx in-block; K=100
// f32 dot + RBF epilogue.
// ---------------------------------------------------------------------------
__global__ __launch_bounds__(256) void graph_kernel(
    const float* __restrict__ wm, const float* __restrict__ cv,
    const float* __restrict__ sigma, float* __restrict__ graph) {
  __shared__ __align__(16) float As[64][108];
  __shared__ __align__(16) float Bs[64][108];
  __shared__ float xs[64], ys[64];
  int bx = blockIdx.x, by = blockIdx.y;
  int t = threadIdx.x;
#pragma unroll
  for (int l = 0; l < 7; ++l) {
    int idx = l * 256 + t;
    if (idx < 1600) {                 // 64 rows * 25 float4
      int row = idx / 25, c4 = (idx - row * 25) * 4;
      float4 wa = *(const float4*)&wm[(by * 64 + row) * AA + c4];
      float4 ca = *(const float4*)&cv[(by * 64 + row) * AA + c4];
      *(float4*)&As[row][c4] =
          make_float4(wa.x * ca.x, wa.y * ca.y, wa.z * ca.z, wa.w * ca.w);
      float4 wb = *(const float4*)&wm[(bx * 64 + row) * AA + c4];
      float4 cb = *(const float4*)&cv[(bx * 64 + row) * AA + c4];
      *(float4*)&Bs[row][c4] =
          make_float4(wb.x * cb.x, wb.y * cb.y, wb.z * cb.z, wb.w * cb.w);
    }
  }
  __syncthreads();
  if (t < 64) {
    float s = 0.0f;
    for (int k4 = 0; k4 < 25; ++k4) {
      float4 q = *(const float4*)&As[t][k4 * 4];
      s += q.x * q.x + q.y * q.y + q.z * q.z + q.w * q.w;
    }
    xs[t] = s;
  } else if (t < 128) {
    int r = t - 64;
    float s = 0.0f;
    for (int k4 = 0; k4 < 25; ++k4) {
      float4 q = *(const float4*)&Bs[r][k4 * 4];
      s += q.x * q.x + q.y * q.y + q.z * q.z + q.w * q.w;
    }
    ys[r] = s;
  }
  __syncthreads();
  int tx = t & 15, ty = t >> 4;
  float acc[4][4] = {{0.0f}};
#pragma unroll 5
  for (int k4 = 0; k4 < 25; ++k4) {
    int k = k4 * 4;
    float4 a_[4], b_[4];
#pragma unroll
    for (int ii = 0; ii < 4; ++ii) a_[ii] = *(const float4*)&As[ty + 16 * ii][k];
#pragma unroll
    for (int jj = 0; jj < 4; ++jj) b_[jj] = *(const float4*)&Bs[tx + 16 * jj][k];
#pragma unroll
    for (int ii = 0; ii < 4; ++ii)
#pragma unroll
      for (int jj = 0; jj < 4; ++jj)
        acc[ii][jj] += a_[ii].x * b_[jj].x + a_[ii].y * b_[jj].y +
                       a_[ii].z * b_[jj].z + a_[ii].w * b_[jj].w;
  }
  float s = *sigma;
  float inv2s2 = 0.5f / (s * s);
#pragma unroll
  for (int ii = 0; ii < 4; ++ii) {
    int gi = by * 64 + ty + 16 * ii;
    float xi = xs[ty + 16 * ii];
#pragma unroll
    for (int jj = 0; jj < 4; ++jj) {
      int gj = bx * 64 + tx + 16 * jj;
      float sq = fmaxf(xi + ys[tx + 16 * jj] - 2.0f * acc[ii][jj], 0.0f);
      graph[gi * NN + gj] = __expf(-(sq * sq) * inv2s2);
    }
  }
}

__global__ void finalize_kernel(const float* __restrict__ sum_acc,
                                float* __restrict__ out) {
  if (threadIdx.x == 0)
    *out = (*sum_acc - 204800.0f) / 204800.0f;  // (sum - N*100) / (N*A)
}

// ---------------------------------------------------------------------------
extern "C" void kernel_launch(void* const* d_in, const int* in_sizes, int n_in,
                              void* d_out, int out_size, void* d_ws, size_t ws_size,
                              hipStream_t stream) {
  (void)in_sizes; (void)n_in; (void)out_size;
  const float* mg    = (const float*)d_in[0];
  const float* nw    = (const float*)d_in[1];
  const float* wm    = (const float*)d_in[2];
  const float* sigma = (const float*)d_in[3];
  float* out        = (float*)d_out;
  float* cv_out     = out;            // 2048*100
  float* scalar_out = out + 204800;   // 1
  float* graph_out  = out + 204801;   // 2048*2048

  float* W = (float*)d_ws;
  float* sum_acc = W;                 // 1 float
  int* anchors   = (int*)(W + 4);     // 100 ints
  float* dist;
  if (ws_size >= (size_t)(256 + (size_t)NN * NN) * sizeof(float)) {
    dist = W + 256;                   // 16 MB scratch
  } else {
    // Fallback: alias dist onto the consensus_graph output region (4B-aligned —
    // every global access to dist is scalar b32). graph_kernel fully overwrites
    // it AFTER cv_kernel has extracted the anchor columns.
    dist = graph_out;
  }

  hipMemsetAsync(sum_acc, 0, sizeof(float), stream);
  build_w_kernel<<<dim3(NT, NT), 256, 0, stream>>>(mg, nw, dist);
  fw_close0<<<1, 256, 0, stream>>>(dist);
  for (int r = 0; r < NT; ++r) {
    fw_p2<<<dim3(NT, 2), 256, 0, stream>>>(dist, r);
    fw_p3<<<dim3(NT, NT), 256, 0, stream>>>(dist, r);
  }
  anchors_kernel<<<NN / 64, 256, 0, stream>>>(nw, anchors);
  cv_kernel<<<800, 256, 0, stream>>>(dist, anchors, cv_out, sum_acc);
  graph_kernel<<<dim3(NT, NT), 256, 0, stream>>>(wm, cv_out, sigma, graph_out);
  finalize_kernel<<<1, 64, 0, stream>>>(sum_acc, scalar_out);
}